// Round 1
// baseline (36.577 us; speedup 1.0000x reference)
//
#include <hip/hip_runtime.h>

// Problem shape (from reference setup_inputs): x = (32, 1024, 28, 28) fp32.
#define B_DIM 32
#define C_DIM 1024
#define N_DIM 784                       // 28*28
#define TOTAL_ELEMS (32LL * 1024LL * 784LL)   // 25,690,112 (divisible by 4)

// Fused kernel.
//  - alpha == 0 fast path: out = x  (pure fp32 copy, memory-bound).
//  - alpha != 0 general path: per row (b,c):
//      G_cd = dot(q_c, q_d);  attention = softmax(-G) (shift-invariance:
//      softmax(rowmax(G)-G) == softmax(-G));  out = alpha * (A @ q) + x.
//    Numerically stable (subtract row max of -G). Correct for any alpha,
//    never executed for this problem's inputs (alpha = 0).
__global__ __launch_bounds__(256)
void AttentionMechanism_67585605370569_kernel(const float* __restrict__ x,
                                              const float* __restrict__ alpha,
                                              float* __restrict__ out) {
    const float a = alpha[0];           // uniform scalar load

    if (a == 0.0f) {
        // -------- fast path: out = 0*attn + x = x --------
        const float4* __restrict__ x4 = reinterpret_cast<const float4*>(x);
        float4* __restrict__ o4       = reinterpret_cast<float4*>(out);
        const long long n4 = TOTAL_ELEMS / 4;
        const long long stride = (long long)gridDim.x * blockDim.x;
        for (long long i = (long long)blockIdx.x * blockDim.x + threadIdx.x;
             i < n4; i += stride) {
            o4[i] = x4[i];
        }
        return;
    }

    // -------- general path: full attention (alpha != 0) --------
    __shared__ float qc[N_DIM];     // the query row q_c (3.1 KB)
    __shared__ float p[C_DIM];      // scores -> probabilities (4 KB)
    __shared__ float red[256];      // block reduction scratch

    const int nrows = B_DIM * C_DIM;
    for (int row = blockIdx.x; row < nrows; row += gridDim.x) {
        const int b = row / C_DIM;
        const int c = row % C_DIM;
        const float* __restrict__ qb = x + (long long)b * C_DIM * N_DIM;

        // stage q_c into LDS
        for (int n = threadIdx.x; n < N_DIM; n += blockDim.x)
            qc[n] = qb[(long long)c * N_DIM + n];
        __syncthreads();

        // pass 1: s_d = -dot(q_c, q_d)
        for (int d = threadIdx.x; d < C_DIM; d += blockDim.x) {
            const float* __restrict__ qd = qb + (long long)d * N_DIM;
            float acc = 0.0f;
            for (int n = 0; n < N_DIM; ++n) acc = fmaf(qc[n], qd[n], acc);
            p[d] = -acc;
        }
        __syncthreads();

        // row max of s (for stable softmax)
        float m = -3.402823466e38f;
        for (int d = threadIdx.x; d < C_DIM; d += blockDim.x) m = fmaxf(m, p[d]);
        red[threadIdx.x] = m;
        __syncthreads();
        for (int s = 128; s > 0; s >>= 1) {
            if ((int)threadIdx.x < s)
                red[threadIdx.x] = fmaxf(red[threadIdx.x], red[threadIdx.x + s]);
            __syncthreads();
        }
        m = red[0];
        __syncthreads();

        // exponentiate + row sum
        float lsum = 0.0f;
        for (int d = threadIdx.x; d < C_DIM; d += blockDim.x) {
            const float e = __expf(p[d] - m);
            p[d] = e;
            lsum += e;
        }
        red[threadIdx.x] = lsum;
        __syncthreads();
        for (int s = 128; s > 0; s >>= 1) {
            if ((int)threadIdx.x < s) red[threadIdx.x] += red[threadIdx.x + s];
            __syncthreads();
        }
        const float inv_l = 1.0f / red[0];
        __syncthreads();

        // pass 2: out[c][n] = a * (sum_d p_d * q_d[n]) * inv_l + x[c][n]
        for (int n = threadIdx.x; n < N_DIM; n += blockDim.x) {
            float acc = 0.0f;
            for (int d = 0; d < C_DIM; ++d)
                acc = fmaf(p[d], qb[(long long)d * N_DIM + n], acc);
            out[(long long)b * C_DIM * N_DIM + (long long)c * N_DIM + n] =
                a * acc * inv_l + qc[n];
        }
        __syncthreads();
    }
}

extern "C" void kernel_launch(void* const* d_in, const int* in_sizes, int n_in,
                              void* d_out, int out_size, void* d_ws, size_t ws_size,
                              hipStream_t stream) {
    const float* x     = (const float*)d_in[0];
    const float* alpha = (const float*)d_in[1];
    float* out         = (float*)d_out;

    // 2048 blocks x 256 threads:
    //  - copy path: grid-stride float4, ~12 iters/thread, saturates HBM.
    //  - general path: row-per-block with gridDim stride over 32768 rows.
    AttentionMechanism_67585605370569_kernel<<<2048, 256, 0, stream>>>(x, alpha, out);
}

// Round 3
// 36.205 us; speedup vs baseline: 1.0103x; 1.0103x over previous
//
#include <hip/hip_runtime.h>

// Problem shape (from reference setup_inputs): x = (32, 1024, 28, 28) fp32.
#define B_DIM 32
#define C_DIM 1024
#define N_DIM 784                       // 28*28
#define TOTAL_ELEMS (32LL * 1024LL * 784LL)   // 25,690,112 (divisible by 4)

// Native vector type — __builtin_nontemporal_store rejects HIP_vector_type.
typedef float fvec4 __attribute__((ext_vector_type(4)));

// Fused kernel.
//  - alpha == 0 fast path: out = x (pure fp32 copy). Non-temporal stores keep
//    the output stream OUT of the 256 MiB Infinity Cache so x (102.8 MB) stays
//    LLC-resident across graph replays -> reads come from LLC, HBM sees only
//    the write stream. Unroll x4 for 4 independent loads in flight per thread.
//  - alpha != 0 general path: per row (b,c):
//      G_cd = dot(q_c, q_d);  attention = softmax(-G) (shift-invariance:
//      softmax(rowmax(G)-G) == softmax(-G));  out = alpha * (A @ q) + x.
//    Correct for any alpha; never executed for this problem's inputs.
__global__ __launch_bounds__(256)
void AttentionMechanism_67585605370569_kernel(const float* __restrict__ x,
                                              const float* __restrict__ alpha,
                                              float* __restrict__ out) {
    const float a = alpha[0];           // uniform scalar load

    if (a == 0.0f) {
        // -------- fast path: out = 0*attn + x = x --------
        const fvec4* __restrict__ x4 = reinterpret_cast<const fvec4*>(x);
        fvec4* __restrict__ o4       = reinterpret_cast<fvec4*>(out);
        const long long n4 = TOTAL_ELEMS / 4;                 // 6,422,528
        const long long stride = (long long)gridDim.x * blockDim.x;  // 524,288
        long long i = (long long)blockIdx.x * blockDim.x + threadIdx.x;

        // unroll x4: 4 independent loads in flight, then 4 nt stores
        for (; i + 3 * stride < n4; i += 4 * stride) {
            const fvec4 a0 = x4[i];
            const fvec4 a1 = x4[i + stride];
            const fvec4 a2 = x4[i + 2 * stride];
            const fvec4 a3 = x4[i + 3 * stride];
            __builtin_nontemporal_store(a0, &o4[i]);
            __builtin_nontemporal_store(a1, &o4[i + stride]);
            __builtin_nontemporal_store(a2, &o4[i + 2 * stride]);
            __builtin_nontemporal_store(a3, &o4[i + 3 * stride]);
        }
        for (; i < n4; i += stride) {
            const fvec4 v = x4[i];
            __builtin_nontemporal_store(v, &o4[i]);
        }
        return;
    }

    // -------- general path: full attention (alpha != 0) --------
    __shared__ float qc[N_DIM];     // the query row q_c (3.1 KB)
    __shared__ float p[C_DIM];      // scores -> probabilities (4 KB)
    __shared__ float red[256];      // block reduction scratch

    const int nrows = B_DIM * C_DIM;
    for (int row = blockIdx.x; row < nrows; row += gridDim.x) {
        const int b = row / C_DIM;
        const int c = row % C_DIM;
        const float* __restrict__ qb = x + (long long)b * C_DIM * N_DIM;

        // stage q_c into LDS
        for (int n = threadIdx.x; n < N_DIM; n += blockDim.x)
            qc[n] = qb[(long long)c * N_DIM + n];
        __syncthreads();

        // pass 1: s_d = -dot(q_c, q_d)
        for (int d = threadIdx.x; d < C_DIM; d += blockDim.x) {
            const float* __restrict__ qd = qb + (long long)d * N_DIM;
            float acc = 0.0f;
            for (int n = 0; n < N_DIM; ++n) acc = fmaf(qc[n], qd[n], acc);
            p[d] = -acc;
        }
        __syncthreads();

        // row max of s (for stable softmax)
        float m = -3.402823466e38f;
        for (int d = threadIdx.x; d < C_DIM; d += blockDim.x) m = fmaxf(m, p[d]);
        red[threadIdx.x] = m;
        __syncthreads();
        for (int s = 128; s > 0; s >>= 1) {
            if ((int)threadIdx.x < s)
                red[threadIdx.x] = fmaxf(red[threadIdx.x], red[threadIdx.x + s]);
            __syncthreads();
        }
        m = red[0];
        __syncthreads();

        // exponentiate + row sum
        float lsum = 0.0f;
        for (int d = threadIdx.x; d < C_DIM; d += blockDim.x) {
            const float e = __expf(p[d] - m);
            p[d] = e;
            lsum += e;
        }
        red[threadIdx.x] = lsum;
        __syncthreads();
        for (int s = 128; s > 0; s >>= 1) {
            if ((int)threadIdx.x < s) red[threadIdx.x] += red[threadIdx.x + s];
            __syncthreads();
        }
        const float inv_l = 1.0f / red[0];
        __syncthreads();

        // pass 2: out[c][n] = a * (sum_d p_d * q_d[n]) * inv_l + x[c][n]
        for (int n = threadIdx.x; n < N_DIM; n += blockDim.x) {
            float acc = 0.0f;
            for (int d = 0; d < C_DIM; ++d)
                acc = fmaf(p[d], qb[(long long)d * N_DIM + n], acc);
            out[(long long)b * C_DIM * N_DIM + (long long)c * N_DIM + n] =
                a * acc * inv_l + qc[n];
        }
        __syncthreads();
    }
}

extern "C" void kernel_launch(void* const* d_in, const int* in_sizes, int n_in,
                              void* d_out, int out_size, void* d_ws, size_t ws_size,
                              hipStream_t stream) {
    const float* x     = (const float*)d_in[0];
    const float* alpha = (const float*)d_in[1];
    float* out         = (float*)d_out;

    // 2048 blocks x 256 threads = 8 blocks/CU -> 32 waves/CU (max occupancy).
    // Copy path: grid-stride float4 x4-unrolled; general path: row-per-block.
    AttentionMechanism_67585605370569_kernel<<<2048, 256, 0, stream>>>(x, alpha, out);
}

// Round 4
// 35.460 us; speedup vs baseline: 1.0315x; 1.0210x over previous
//
#include <hip/hip_runtime.h>

// Problem shape (from reference setup_inputs): x = (32, 1024, 28, 28) fp32.
#define B_DIM 32
#define C_DIM 1024
#define N_DIM 784                       // 28*28
#define TOTAL_ELEMS (32LL * 1024LL * 784LL)   // 25,690,112
#define TOTAL_BYTES (TOTAL_ELEMS * 4LL)       // 102,760,448 B

// Strategy:
//   out = alpha*attn(x) + x, and alpha is a runtime device scalar (== 0 for
//   this problem's inputs). We ALWAYS enqueue a driver D2D copy out <- x
//   (hipMemcpyAsync is graph-capture-legal; blit/SDMA path benches ~85% of
//   8 TB/s vs our CU copy's 5.7 TB/s). Then a kernel:
//     - alpha == 0: return immediately (memcpy already produced out = x).
//     - alpha != 0: compute full attention and overwrite out (reads only x,
//       so the earlier copy is dead but harmless). Correct for any alpha.
__global__ __launch_bounds__(256)
void AttentionMechanism_67585605370569_kernel(const float* __restrict__ x,
                                              const float* __restrict__ alpha,
                                              float* __restrict__ out) {
    const float a = alpha[0];           // uniform scalar load
    if (a == 0.0f) return;              // out = x already done by memcpy

    // -------- general path: full attention (alpha != 0) --------
    __shared__ float qc[N_DIM];     // the query row q_c (3.1 KB)
    __shared__ float p[C_DIM];      // scores -> probabilities (4 KB)
    __shared__ float red[256];      // block reduction scratch

    const int nrows = B_DIM * C_DIM;
    for (int row = blockIdx.x; row < nrows; row += gridDim.x) {
        const int b = row / C_DIM;
        const int c = row % C_DIM;
        const float* __restrict__ qb = x + (long long)b * C_DIM * N_DIM;

        // stage q_c into LDS
        for (int n = threadIdx.x; n < N_DIM; n += blockDim.x)
            qc[n] = qb[(long long)c * N_DIM + n];
        __syncthreads();

        // pass 1: s_d = -dot(q_c, q_d)   (softmax(rowmax(G)-G) == softmax(-G))
        for (int d = threadIdx.x; d < C_DIM; d += blockDim.x) {
            const float* __restrict__ qd = qb + (long long)d * N_DIM;
            float acc = 0.0f;
            for (int n = 0; n < N_DIM; ++n) acc = fmaf(qc[n], qd[n], acc);
            p[d] = -acc;
        }
        __syncthreads();

        // row max of s (for stable softmax)
        float m = -3.402823466e38f;
        for (int d = threadIdx.x; d < C_DIM; d += blockDim.x) m = fmaxf(m, p[d]);
        red[threadIdx.x] = m;
        __syncthreads();
        for (int s = 128; s > 0; s >>= 1) {
            if ((int)threadIdx.x < s)
                red[threadIdx.x] = fmaxf(red[threadIdx.x], red[threadIdx.x + s]);
            __syncthreads();
        }
        m = red[0];
        __syncthreads();

        // exponentiate + row sum
        float lsum = 0.0f;
        for (int d = threadIdx.x; d < C_DIM; d += blockDim.x) {
            const float e = __expf(p[d] - m);
            p[d] = e;
            lsum += e;
        }
        red[threadIdx.x] = lsum;
        __syncthreads();
        for (int s = 128; s > 0; s >>= 1) {
            if ((int)threadIdx.x < s) red[threadIdx.x] += red[threadIdx.x + s];
            __syncthreads();
        }
        const float inv_l = 1.0f / red[0];
        __syncthreads();

        // pass 2: out[c][n] = a * (sum_d p_d * q_d[n]) * inv_l + x[c][n]
        for (int n = threadIdx.x; n < N_DIM; n += blockDim.x) {
            float acc = 0.0f;
            for (int d = 0; d < C_DIM; ++d)
                acc = fmaf(p[d], qb[(long long)d * N_DIM + n], acc);
            out[(long long)b * C_DIM * N_DIM + (long long)c * N_DIM + n] =
                a * acc * inv_l + qc[n];
        }
        __syncthreads();
    }
}

extern "C" void kernel_launch(void* const* d_in, const int* in_sizes, int n_in,
                              void* d_out, int out_size, void* d_ws, size_t ws_size,
                              hipStream_t stream) {
    const float* x     = (const float*)d_in[0];
    const float* alpha = (const float*)d_in[1];
    float* out         = (float*)d_out;

    // Driver-level D2D copy: out = x (the alpha==0 result). Blit/SDMA path.
    hipMemcpyAsync(out, x, (size_t)TOTAL_BYTES, hipMemcpyDeviceToDevice, stream);

    // Conditional attention: no-op when alpha==0, full recompute otherwise.
    AttentionMechanism_67585605370569_kernel<<<2048, 256, 0, stream>>>(x, alpha, out);
}

// Round 5
// 35.391 us; speedup vs baseline: 1.0335x; 1.0020x over previous
//
#include <hip/hip_runtime.h>

// Problem shape (from reference setup_inputs): x = (32, 1024, 28, 28) fp32.
#define B_DIM 32
#define C_DIM 1024
#define N_DIM 784                       // 28*28
#define TOTAL_ELEMS (32LL * 1024LL * 784LL)   // 25,690,112
#define TOTAL_BYTES (TOTAL_ELEMS * 4LL)       // 102,760,448 B

// Strategy:
//   out = alpha*attn(x) + x, alpha a runtime device scalar (== 0 here).
//   1) hipMemcpyAsync(out <- x): driver blit copy, the alpha==0 result.
//   2) conditional kernel: no-op when alpha==0 (just one scalar read per
//      wave); full attention overwrite when alpha != 0 (grid-stride over
//      rows, so correct at ANY grid size — we use a small grid to make the
//      dead dispatch cheap in the common alpha==0 case).
__global__ __launch_bounds__(256)
void AttentionMechanism_67585605370569_kernel(const float* __restrict__ x,
                                              const float* __restrict__ alpha,
                                              float* __restrict__ out) {
    const float a = alpha[0];           // uniform scalar load
    if (a == 0.0f) return;              // out = x already produced by memcpy

    // -------- general path: full attention (alpha != 0) --------
    __shared__ float qc[N_DIM];     // the query row q_c (3.1 KB)
    __shared__ float p[C_DIM];      // scores -> probabilities (4 KB)
    __shared__ float red[256];      // block reduction scratch

    const int nrows = B_DIM * C_DIM;
    for (int row = blockIdx.x; row < nrows; row += gridDim.x) {
        const int b = row / C_DIM;
        const int c = row % C_DIM;
        const float* __restrict__ qb = x + (long long)b * C_DIM * N_DIM;

        // stage q_c into LDS
        for (int n = threadIdx.x; n < N_DIM; n += blockDim.x)
            qc[n] = qb[(long long)c * N_DIM + n];
        __syncthreads();

        // pass 1: s_d = -dot(q_c, q_d)   (softmax(rowmax(G)-G) == softmax(-G))
        for (int d = threadIdx.x; d < C_DIM; d += blockDim.x) {
            const float* __restrict__ qd = qb + (long long)d * N_DIM;
            float acc = 0.0f;
            for (int n = 0; n < N_DIM; ++n) acc = fmaf(qc[n], qd[n], acc);
            p[d] = -acc;
        }
        __syncthreads();

        // row max of s (for stable softmax)
        float m = -3.402823466e38f;
        for (int d = threadIdx.x; d < C_DIM; d += blockDim.x) m = fmaxf(m, p[d]);
        red[threadIdx.x] = m;
        __syncthreads();
        for (int s = 128; s > 0; s >>= 1) {
            if ((int)threadIdx.x < s)
                red[threadIdx.x] = fmaxf(red[threadIdx.x], red[threadIdx.x + s]);
            __syncthreads();
        }
        m = red[0];
        __syncthreads();

        // exponentiate + row sum
        float lsum = 0.0f;
        for (int d = threadIdx.x; d < C_DIM; d += blockDim.x) {
            const float e = __expf(p[d] - m);
            p[d] = e;
            lsum += e;
        }
        red[threadIdx.x] = lsum;
        __syncthreads();
        for (int s = 128; s > 0; s >>= 1) {
            if ((int)threadIdx.x < s) red[threadIdx.x] += red[threadIdx.x + s];
            __syncthreads();
        }
        const float inv_l = 1.0f / red[0];
        __syncthreads();

        // pass 2: out[c][n] = a * (sum_d p_d * q_d[n]) * inv_l + x[c][n]
        for (int n = threadIdx.x; n < N_DIM; n += blockDim.x) {
            float acc = 0.0f;
            for (int d = 0; d < C_DIM; ++d)
                acc = fmaf(p[d], qb[(long long)d * N_DIM + n], acc);
            out[(long long)b * C_DIM * N_DIM + (long long)c * N_DIM + n] =
                a * acc * inv_l + qc[n];
        }
        __syncthreads();
    }
}

extern "C" void kernel_launch(void* const* d_in, const int* in_sizes, int n_in,
                              void* d_out, int out_size, void* d_ws, size_t ws_size,
                              hipStream_t stream) {
    const float* x     = (const float*)d_in[0];
    const float* alpha = (const float*)d_in[1];
    float* out         = (float*)d_out;

    // Driver-level D2D copy: out = x (the alpha==0 result). Blit/SDMA path.
    hipMemcpyAsync(out, x, (size_t)TOTAL_BYTES, hipMemcpyDeviceToDevice, stream);

    // Conditional attention: no-op when alpha==0. Small grid = cheap dead
    // dispatch; grid-stride keeps the alpha!=0 path correct at any grid.
    AttentionMechanism_67585605370569_kernel<<<256, 256, 0, stream>>>(x, alpha, out);
}